// Round 7
// baseline (337.677 us; speedup 1.0000x reference)
//
#include <hip/hip_runtime.h>

#define B_SZ 8
#define S_SZ 1024
#define DM   1024
#define NH   16
#define DK   64

typedef __bf16 bf16;
typedef __bf16 bf16x8 __attribute__((ext_vector_type(8)));
typedef float  f32x4  __attribute__((ext_vector_type(4)));

__device__ __forceinline__ f32x4 mfma16x16x32(bf16x8 a, bf16x8 b, f32x4 c) {
    return __builtin_amdgcn_mfma_f32_16x16x32_bf16(a, b, c, 0, 0, 0);
}

typedef const __attribute__((address_space(1))) void* gptr_t;
typedef __attribute__((address_space(3))) void*       sptr_t;
__device__ __forceinline__ void async_cp16(const void* g, void* s) {
    __builtin_amdgcn_global_load_lds((gptr_t)g, (sptr_t)s, 16, 0, 0);
}

template<int N> __device__ __forceinline__ void wait_vmcnt() {
    asm volatile("s_waitcnt vmcnt(%0)" :: "n"(N) : "memory");
}
__device__ __forceinline__ void block_barrier() {
    __builtin_amdgcn_sched_barrier(0);
    asm volatile("" ::: "memory");
    __builtin_amdgcn_s_barrier();
    asm volatile("" ::: "memory");
    __builtin_amdgcn_sched_barrier(0);
}

// ---------------------------------------------------------------------------
// Kernel 0: fp32 -> bf16 convert for X (z<3) and W (z>=3).
// ---------------------------------------------------------------------------
__global__ __launch_bounds__(256)
void cvt_kernel(const float* __restrict__ x0, const float* __restrict__ x1,
                const float* __restrict__ x2, const float* __restrict__ w0,
                const float* __restrict__ w1, const float* __restrict__ w2,
                bf16* __restrict__ xb, bf16* __restrict__ wb)
{
    const int z = blockIdx.y;
    const float* src;
    bf16* dst;
    int n;
    if (z < 3) {
        src = (z == 0) ? x0 : (z == 1) ? x1 : x2;
        dst = xb + (size_t)z * (8u * 1024 * 1024);
        n = 8 * 1024 * 1024;
    } else {
        const int w = z - 3;
        src = (w == 0) ? w0 : (w == 1) ? w1 : w2;
        dst = wb + (size_t)w * (1024 * 1024);
        n = 1024 * 1024;
    }
    const int idx = (blockIdx.x * 256 + threadIdx.x) * 8;
    if (idx >= n) return;
    const float4 a = *(const float4*)(src + idx);
    const float4 c = *(const float4*)(src + idx + 4);
    union { bf16 h[8]; uint4 u; } pk;
    pk.h[0] = (bf16)a.x; pk.h[1] = (bf16)a.y; pk.h[2] = (bf16)a.z; pk.h[3] = (bf16)a.w;
    pk.h[4] = (bf16)c.x; pk.h[5] = (bf16)c.y; pk.h[6] = (bf16)c.z; pk.h[7] = (bf16)c.w;
    *(uint4*)(dst + idx) = pk.u;
}

// gp fp32 -> bf16 (runs AFTER qkv_gemm; output aliases the dead xb region)
__global__ __launch_bounds__(256)
void cvt_gp_kernel(const float* __restrict__ gp, bf16* __restrict__ gpb)
{
    const int idx = (blockIdx.x * 256 + threadIdx.x) * 8;
    const float4 a = *(const float4*)(gp + idx);
    const float4 c = *(const float4*)(gp + idx + 4);
    union { bf16 h[8]; uint4 u; } pk;
    pk.h[0] = (bf16)a.x; pk.h[1] = (bf16)a.y; pk.h[2] = (bf16)a.z; pk.h[3] = (bf16)a.w;
    pk.h[4] = (bf16)c.x; pk.h[5] = (bf16)c.y; pk.h[6] = (bf16)c.z; pk.h[7] = (bf16)c.w;
    *(uint4*)(gpb + idx) = pk.u;
}

// ---------------------------------------------------------------------------
// Kernel 1: m97-style bf16 GEMM with XOR chunk-swizzled LDS (unchanged).
// ---------------------------------------------------------------------------
__global__ __launch_bounds__(256, 2)
void qkv_gemm(const bf16* __restrict__ xb, const bf16* __restrict__ wb,
              const float* __restrict__ bq, const float* __restrict__ bk,
              const float* __restrict__ bv,
              bf16* __restrict__ qb, bf16* __restrict__ kb,
              bf16* __restrict__ vb)
{
    const int z = blockIdx.z;
    const bf16* A  = xb + (size_t)z * (8u * 1024 * 1024);
    const bf16* Bm = wb + (size_t)z * (1024 * 1024);
    const float* bias = (z == 0) ? bq : (z == 1) ? bk : bv;

    __shared__ bf16 Ash[128 * 64];
    __shared__ bf16 Bsh[128 * 64];

    const int tid  = threadIdx.x;
    const int wid  = tid >> 6;
    const int lane = tid & 63;
    const int quad = lane >> 4;
    const int l16  = lane & 15;
    const int wm   = wid >> 1, wn = wid & 1;
    const int bm   = blockIdx.x, bn = blockIdx.y;

    f32x4 acc[4][4] = {};

    for (int k0 = 0; k0 < DM; k0 += 64) {
        __syncthreads();
        #pragma unroll
        for (int i = 0; i < 4; ++i) {
            const int e   = (i * 256 + tid) * 8;
            const int row = e >> 6;
            const int c   = ((e >> 3) & 7) ^ (row & 7);   // source-chunk swizzle
            async_cp16(A  + (size_t)(bm * 128 + row) * DM + k0 + c * 8, &Ash[e]);
            async_cp16(Bm + (size_t)(bn * 128 + row) * DM + k0 + c * 8, &Bsh[e]);
        }
        __syncthreads();

        #pragma unroll
        for (int ks = 0; ks < 2; ++ks) {
            bf16x8 af[4], bfr[4];
            #pragma unroll
            for (int mi = 0; mi < 4; ++mi) {
                const int row = wm * 64 + mi * 16 + l16;
                af[mi] = *(const bf16x8*)&Ash[row * 64 + (((ks * 4 + quad) ^ (l16 & 7)) << 3)];
            }
            #pragma unroll
            for (int ni = 0; ni < 4; ++ni) {
                const int row = wn * 64 + ni * 16 + l16;
                bfr[ni] = *(const bf16x8*)&Bsh[row * 64 + (((ks * 4 + quad) ^ (l16 & 7)) << 3)];
            }
            #pragma unroll
            for (int mi = 0; mi < 4; ++mi)
                #pragma unroll
                for (int ni = 0; ni < 4; ++ni)
                    acc[mi][ni] = mfma16x16x32(af[mi], bfr[ni], acc[mi][ni]);
        }
    }

    #pragma unroll
    for (int ni = 0; ni < 4; ++ni) {
        const int n    = bn * 128 + wn * 64 + ni * 16 + l16;
        const float bv_ = bias[n];
        const int h = n >> 6, d = n & 63;
        #pragma unroll
        for (int mi = 0; mi < 4; ++mi) {
            const int m0 = bm * 128 + wm * 64 + mi * 16 + quad * 4;
            const int b  = m0 >> 10;
            const int s0 = m0 & 1023;
            if (z == 2) {
                union { bf16 h4[4]; uint2 u; } pk;
                #pragma unroll
                for (int r = 0; r < 4; ++r) pk.h4[r] = (bf16)(acc[mi][ni][r] + bv_);
                *(uint2*)(vb + ((size_t)((b * NH + h) * DK + d)) * S_SZ + s0) = pk.u;
            } else {
                bf16* dst      = (z == 0) ? qb : kb;
                const float sc = (z == 0) ? 0.125f : 1.0f;
                #pragma unroll
                for (int r = 0; r < 4; ++r)
                    dst[((size_t)(b * NH + h) * S_SZ + (s0 + r)) * DK + d] =
                        (bf16)((acc[mi][ni][r] + bv_) * sc);
            }
        }
    }
}

// ---------------------------------------------------------------------------
// Kernel 2: attention — counted-vmcnt pipeline (T4). 3-deep K/V LDS buffers,
// raw s_barrier (NO implicit vmcnt(0) drain), per-iteration s_waitcnt vmcnt(N)
// with N = #VMEM ops program-ordered after STAGE(t+1): STAGE(t+1) gets two
// full COMPUTE phases of latency cover; STAGE(t+2)/(t+3)/gp(t+1) stay in
// flight across barriers. Everything else identical to round-6 (verified).
// ---------------------------------------------------------------------------
__global__ __launch_bounds__(512, 6)
void attn_kernel(const bf16* __restrict__ qb, const bf16* __restrict__ kb,
                 const bf16* __restrict__ vb, const bf16* __restrict__ gpb,
                 float* __restrict__ out)
{
    __shared__ bf16 Ksh[3][64 * 64];   // [key][dim], chunk-swizzled, 8 KB each
    __shared__ bf16 Vsh[3][64 * 64];   // [dim][key], chunk-swizzled, 8 KB each
    __shared__ bf16 Psh[8][16 * 72];   // per-wave P, [q][key], +8 pad
    __shared__ float Lsh[8][16];

    const int tid  = threadIdx.x;
    const int wid  = tid >> 6;         // 0..7
    const int lane = tid & 63;
    const int quad = lane >> 4;
    const int l16  = lane & 15;

    // XCD-locality remap (bijective over 1024 blocks):
    //   b = lid&7 (== XCD under linear round-robin), h = (lid>>3)&15, qt = lid>>7
    const int lid = blockIdx.x + (int)gridDim.x * blockIdx.y;
    const int b   = lid & 7;
    const int h   = (lid >> 3) & (NH - 1);
    const int qt  = lid >> 7;
    const int bh  = b * NH + h;
    const int q0  = qt * 128 + wid * 16;

    // Q as B-operand: B[k=d][n=q]: lane l16 -> q, quad*8+j -> d
    const bf16* qr = qb + ((size_t)bh * S_SZ + q0 + l16) * DK;
    const bf16x8 qf0 = *(const bf16x8*)(qr + quad * 8);
    const bf16x8 qf1 = *(const bf16x8*)(qr + 32 + quad * 8);

    f32x4 acc[4] = {};
    float lpart = 0.0f;

    const bf16* gpq = gpb + ((size_t)b * S_SZ + q0 + l16) * S_SZ;  // gp row q
    const bf16* kbh = kb + (size_t)bh * (S_SZ * DK);
    const bf16* vbh = vb + (size_t)bh * ((size_t)DK * S_SZ);

    // stage tile t (keys t*64..+63) into buffer bufi; 512 threads -> 1 chunk
    // of K and 1 chunk of V each (64x64 bf16 = 512 x 16B). 2 VMEM ops/wave.
    auto STAGE = [&](int t, int bufi) {
        const int e   = tid * 8;               // elements, 0..4088
        const int row = e >> 6;
        const int c   = ((e >> 3) & 7) ^ (row & 7);
        async_cp16(kbh + (size_t)(t * 64 + row) * DK + c * 8, &Ksh[bufi][e]);
        async_cp16(vbh + (size_t)row * S_SZ + t * 64 + c * 8, &Vsh[bufi][e]);
    };
    auto GPLOAD = [&](int t, ushort4 (&g)[4]) {   // 4 VMEM ops/wave
        #pragma unroll
        for (int nb = 0; nb < 4; ++nb)
            g[nb] = *(const ushort4*)(gpq + t * 64 + nb * 16 + quad * 4);
    };
    auto COMPUTE = [&](const bf16* Kb, const bf16* Vb, const ushort4 (&g)[4]) {
        // S^T = K Q^T: lane holds key = nb*16+quad*4+r, q = l16
        f32x4 sc[4];
        #pragma unroll
        for (int nb = 0; nb < 4; ++nb) {
            const int row = nb * 16 + l16;
            const bf16x8 kf0 = *(const bf16x8*)&Kb[row * 64 + ((quad ^ (l16 & 7)) << 3)];
            const bf16x8 kf1 = *(const bf16x8*)&Kb[row * 64 + (((4 + quad) ^ (l16 & 7)) << 3)];
            f32x4 s = {0.0f, 0.0f, 0.0f, 0.0f};
            s = mfma16x16x32(kf0, qf0, s);
            s = mfma16x16x32(kf1, qf1, s);
            sc[nb] = s;
        }
        // p = exp(s), denominator partial, P*gp -> Psh packed
        #pragma unroll
        for (int nb = 0; nb < 4; ++nb) {
            union { bf16 h4[4]; uint2 u; } pk;
            const unsigned short* gu = (const unsigned short*)&g[nb];
            #pragma unroll
            for (int r = 0; r < 4; ++r) {
                const float pv = __expf(sc[nb][r]);
                lpart += pv;
                const float gg = __uint_as_float(((unsigned)gu[r]) << 16);
                pk.h4[r] = (bf16)(pv * gg);
            }
            *(uint2*)&Psh[wid][l16 * 72 + nb * 16 + quad * 4] = pk.u;
        }
        // PV: A = P[q=l16][k], B = V^T
        bf16x8 pf[2];
        #pragma unroll
        for (int j = 0; j < 2; ++j)
            pf[j] = *(const bf16x8*)&Psh[wid][l16 * 72 + j * 32 + quad * 8];
        #pragma unroll
        for (int ni = 0; ni < 4; ++ni) {
            const int vrow = ni * 16 + l16;
            #pragma unroll
            for (int j = 0; j < 2; ++j) {
                const bf16x8 vf =
                    *(const bf16x8*)&Vb[vrow * 64 + (((j * 4 + quad) ^ (l16 & 7)) << 3)];
                acc[ni] = mfma16x16x32(pf[j], vf, acc[ni]);
            }
        }
    };

    ushort4 gpl[2][4];

    // Prologue: 3 stages in flight, gp(0) in regs. Wait only for S(0):
    // after S(0) come S(1)[2] + S(2)[2] + g(0)[4] = 8 newer ops -> vmcnt(8).
    STAGE(0, 0);
    STAGE(1, 1);
    STAGE(2, 2);
    GPLOAD(0, gpl[0]);
    wait_vmcnt<8>();
    block_barrier();

    // KN(T): #VMEM ops program-ordered after STAGE(T+1) at the wait point:
    //   g(T)[4] + S(T+2)[2] + g(T+1)[4] + S(T+3)[2], dropping out-of-range.
#define KN(T) (4 + ((T)+2 < 16 ? 2 : 0) + ((T)+1 < 16 ? 4 : 0) + ((T)+3 < 16 ? 2 : 0))
#define STEP(T) do {                                                      \
        if ((T) + 1 < 16) GPLOAD((T) + 1, gpl[((T) + 1) & 1]);            \
        COMPUTE(Ksh[(T) % 3], Vsh[(T) % 3], gpl[(T) & 1]);                \
        block_barrier();              /* all waves done reading buf T%3 */ \
        if ((T) + 3 < 16) STAGE((T) + 3, (T) % 3);                        \
        if ((T) < 15) { wait_vmcnt<KN(T)>(); block_barrier(); }           \
    } while (0)

    STEP(0);  STEP(1);  STEP(2);  STEP(3);
    STEP(4);  STEP(5);  STEP(6);  STEP(7);
    STEP(8);  STEP(9);  STEP(10); STEP(11);
    STEP(12); STEP(13); STEP(14); STEP(15);
#undef STEP
#undef KN

    // denominator: sum across quads (keys), broadcast via LDS
    lpart += __shfl_xor(lpart, 16, 64);
    lpart += __shfl_xor(lpart, 32, 64);
    if (quad == 0) Lsh[wid][l16] = 1.0f / lpart;
    __syncthreads();

    #pragma unroll
    for (int r = 0; r < 4; ++r) {
        const float inv = Lsh[wid][quad * 4 + r];
        float* orow = out + ((size_t)b * S_SZ + q0 + quad * 4 + r) * DM + h * DK;
        #pragma unroll
        for (int ni = 0; ni < 4; ++ni)
            orow[ni * 16 + l16] = acc[ni][r] * inv;
    }
}

extern "C" void kernel_launch(void* const* d_in, const int* in_sizes, int n_in,
                              void* d_out, int out_size, void* d_ws, size_t ws_size,
                              hipStream_t stream) {
    const float* queries = (const float*)d_in[0];
    const float* keys    = (const float*)d_in[1];
    const float* values  = (const float*)d_in[2];
    const float* gp      = (const float*)d_in[3];
    // d_in[4] attention_mask: dead code in reference
    const float* Wq = (const float*)d_in[5];
    const float* bq = (const float*)d_in[6];
    const float* Wk = (const float*)d_in[7];
    const float* bk = (const float*)d_in[8];
    const float* Wv = (const float*)d_in[9];
    const float* bv = (const float*)d_in[10];
    float* out = (float*)d_out;

    // ws (bf16 elems): Xb 3x8M | Wb 3x1M | qb,kb,vb 3x8M. gpb reuses xb
    // (xb is dead after qkv_gemm; cvt_gp runs after it in stream order).
    bf16* xb = (bf16*)d_ws;
    bf16* wb = xb + (size_t)3 * 8 * 1024 * 1024;
    bf16* qb = wb + (size_t)3 * 1024 * 1024;
    bf16* kb = qb + (size_t)B_SZ * NH * S_SZ * DK;
    bf16* vb = kb + (size_t)B_SZ * NH * S_SZ * DK;
    bf16* gpb = xb;
    (void)ws_size; (void)in_sizes; (void)n_in; (void)out_size;

    dim3 gc(4096, 6);
    cvt_kernel<<<gc, 256, 0, stream>>>(queries, keys, values, Wq, Wk, Wv, xb, wb);

    dim3 g1(64, 8, 3);
    qkv_gemm<<<g1, 256, 0, stream>>>(xb, wb, bq, bk, bv, qb, kb, vb);

    cvt_gp_kernel<<<dim3(4096), 256, 0, stream>>>(gp, gpb);

    dim3 g2(B_SZ * NH /*128*/, S_SZ / 128 /*8*/, 1);
    attn_kernel<<<g2, 512, 0, stream>>>(qb, kb, vb, gpb, out);
}